// Round 3
// baseline (839.523 us; speedup 1.0000x reference)
//
#include <hip/hip_runtime.h>
#include <hip/hip_bf16.h>
#include <stdint.h>

// MoE: N=8192 tokens, D=2048, E=8 experts, top-2 routing.
// memset(cnt,out) -> prep (gate + x->bf16 fused | W->bf16, one concurrent grid) ->
// grouped bf16 MFMA GEMM 256x256, BK=64, 8-phase-per-2-Ktiles counted-vmcnt schedule
// (T1 XCD swizzle + T2 LDS swizzle + T3/T4 phases/counted vmcnt + T5 setprio),
// fused bias+ReLU+gate-weight epilogue, fp32 atomicAdd combine.

#define N_TOK 8192
#define DIM   2048
#define NEXP  8

#define BM 256
#define BN 256
#define BK 64
#define KT (DIM / BK)   // 32 K-tiles

typedef __attribute__((ext_vector_type(8))) short short8;
typedef __attribute__((ext_vector_type(4))) float f32x4;

#define MFMA16 __builtin_amdgcn_mfma_f32_16x16x32_bf16

// ---- workspace layout (bytes) ----
#define OFF_CNT 0
#define OFF_TOK 1024
#define OFF_WL  (OFF_TOK + N_TOK*NEXP*4)
#define OFF_XB  (OFF_WL + N_TOK*NEXP*4)
#define OFF_WB  (OFF_XB + (size_t)N_TOK*DIM*2)

__device__ __forceinline__ void gload_lds16(const void* g, void* l) {
  __builtin_amdgcn_global_load_lds(
      (const __attribute__((address_space(1))) void*)g,
      (__attribute__((address_space(3))) void*)l, 16, 0, 0);
}

// ---------------- prep: blocks [0,2048) = gate (+ x->bf16); [2048,4096) = W->bf16 ---
__global__ __launch_bounds__(256) void prep_kernel(
    const float* __restrict__ x, const float* __restrict__ We,
    const float* __restrict__ wg, const float* __restrict__ bg,
    __hip_bfloat16* __restrict__ xb, __hip_bfloat16* __restrict__ wb,
    int* __restrict__ cnt, int* __restrict__ toklist, float* __restrict__ wlist) {
  if (blockIdx.x >= N_TOK / 4) {
    // ---- W conversion: 2048 blocks, grid-stride over 8.4M float4 ----
    const int n4 = NEXP * DIM * DIM / 4;
    const int stride = 2048 * 256;
    for (int i = (blockIdx.x - N_TOK / 4) * 256 + threadIdx.x; i < n4; i += stride) {
      float4 v = reinterpret_cast<const float4*>(We)[i];
      union { ushort4 u; __hip_bfloat16 h[4]; } cv;
      cv.h[0] = __float2bfloat16(v.x);
      cv.h[1] = __float2bfloat16(v.y);
      cv.h[2] = __float2bfloat16(v.z);
      cv.h[3] = __float2bfloat16(v.w);
      reinterpret_cast<ushort4*>(wb)[i] = cv.u;
    }
    return;
  }
  // ---- gating: one wave per token, fp32; fused x->bf16 cast ----
  const int wave = threadIdx.x >> 6;
  const int lane = threadIdx.x & 63;
  const int t = blockIdx.x * 4 + wave;
  const float4* xr = reinterpret_cast<const float4*>(x + (size_t)t * DIM);
  ushort4* xo = reinterpret_cast<ushort4*>(xb + (size_t)t * DIM);
  float acc[NEXP];
#pragma unroll
  for (int e = 0; e < NEXP; ++e) acc[e] = 0.f;
#pragma unroll
  for (int j = 0; j < DIM / 4 / 64; ++j) {     // 8 iters
    float4 xv = xr[lane + 64 * j];
    union { ushort4 u; __hip_bfloat16 h[4]; } cv;
    cv.h[0] = __float2bfloat16(xv.x);
    cv.h[1] = __float2bfloat16(xv.y);
    cv.h[2] = __float2bfloat16(xv.z);
    cv.h[3] = __float2bfloat16(xv.w);
    xo[lane + 64 * j] = cv.u;
#pragma unroll
    for (int e = 0; e < NEXP; ++e) {
      float4 gv = reinterpret_cast<const float4*>(wg + (size_t)e * DIM)[lane + 64 * j];
      acc[e] += xv.x * gv.x + xv.y * gv.y + xv.z * gv.z + xv.w * gv.w;
    }
  }
#pragma unroll
  for (int e = 0; e < NEXP; ++e) {
    float v = acc[e];
#pragma unroll
    for (int off = 32; off > 0; off >>= 1) v += __shfl_down(v, off);
    acc[e] = v;
  }
  if (lane == 0) {
    float lg[NEXP];
#pragma unroll
    for (int e = 0; e < NEXP; ++e) lg[e] = acc[e] + bg[e];
    float m = lg[0];
#pragma unroll
    for (int e = 1; e < NEXP; ++e) m = fmaxf(m, lg[e]);
    float s = 0.f, w[NEXP];
#pragma unroll
    for (int e = 0; e < NEXP; ++e) { w[e] = expf(lg[e] - m); s += w[e]; }
    float inv = 1.f / s;
    int i0 = 0;
#pragma unroll
    for (int e = 1; e < NEXP; ++e) if (lg[e] > lg[i0]) i0 = e;
    int i1 = -1;
#pragma unroll
    for (int e = 0; e < NEXP; ++e)
      if (e != i0 && (i1 < 0 || lg[e] > lg[i1])) i1 = e;
    int p0 = atomicAdd(&cnt[i0], 1);
    toklist[i0 * N_TOK + p0] = t;  wlist[i0 * N_TOK + p0] = w[i0] * inv;
    int p1 = atomicAdd(&cnt[i1], 1);
    toklist[i1 * N_TOK + p1] = t;  wlist[i1 * N_TOK + p1] = w[i1] * inv;
  }
}

// ---------------- grouped GEMM, 8-phase counted-vmcnt schedule ----------------
// 2048 blocks (XCD-swizzled: expert e -> XCD e), 512 threads = 8 waves (2M x 4N).
// LDS K-half-major: s{A,B}[buf][kh][256 rows][4 granules][16B]; stage slot = 16KB.
// Slot order per iter (staging tile t+1 while computing t): A-k0, B-k0, A-k1, B-k1.
// vmcnt(4) at end of phases 1 and 3 => the K-half needed next is landed, 2 slots
// (4 loads/thread) stay in flight across the barrier. Never vmcnt(0) in main loop.
__global__ __launch_bounds__(512, 2) void moe_gemm(
    const __hip_bfloat16* __restrict__ xb, const __hip_bfloat16* __restrict__ wb,
    const float* __restrict__ be, const int* __restrict__ cnt,
    const int* __restrict__ toklist, const float* __restrict__ wlist,
    float* __restrict__ out) {
  const int p = blockIdx.x;                 // 0..2047
  const int l = (p & 7) * 256 + (p >> 3);   // bijective XCD-chunked remap
  const int e  = l >> 8;
  const int ct = (l >> 5) & 7;
  const int tr = l & 31;
  const int ce = cnt[e];
  const int row0 = tr * BM;
  if (row0 >= ce) return;                   // uniform early-exit
  const int bn0 = ct * BN;

  __shared__ __align__(16) char sA[2 * 2 * 256 * 64];  // 64 KB
  __shared__ __align__(16) char sB[2 * 2 * 256 * 64];  // 64 KB
  __shared__ int   sTok[BM];
  __shared__ float sWt[BM];

  const int tid = threadIdx.x;
  if (tid < BM) {
    int r = row0 + tid;
    bool valid = r < ce;
    sTok[tid] = valid ? toklist[e * N_TOK + r] : 0;
    sWt[tid]  = valid ? wlist[e * N_TOK + r] : 0.f;
  }
  __syncthreads();   // full drain: clears all pre-loop vmem so vmcnt counting is exact

  // ---- staging precompute: thread writes granules c0=tid, c1=tid+512 of each slot.
  // LDS granule (r, g_phys) holds logical granule g_log = g_phys ^ ((r>>1)&3)
  // (inverse swizzle applied on the GLOBAL source; reads apply the same XOR).
  const int c0 = tid, c1 = tid + 512;
  const int r0 = c0 >> 2, r1 = c1 >> 2;
  const int g0 = (c0 & 3) ^ ((r0 >> 1) & 3);
  const int g1 = (c1 & 3) ^ ((r1 >> 1) & 3);
  const char* pA0 = (const char*)xb + (size_t)sTok[r0] * (DIM * 2) + g0 * 16;
  const char* pA1 = (const char*)xb + (size_t)sTok[r1] * (DIM * 2) + g1 * 16;
  const char* pB0 = (const char*)wb + (size_t)(e * DIM + bn0 + r0) * (DIM * 2) + g0 * 16;
  const char* pB1 = (const char*)wb + (size_t)(e * DIM + bn0 + r1) * (DIM * 2) + g1 * 16;
  char* dA0 = sA + c0 * 16;  char* dA1 = sA + c1 * 16;
  char* dB0 = sB + c0 * 16;  char* dB1 = sB + c1 * 16;

  auto stageA = [&](int buf, int kh, int kt) {
    const int lo = buf * 32768 + kh * 16384;
    const int go = kt * 128 + kh * 64;
    gload_lds16(pA0 + go, dA0 + lo);
    gload_lds16(pA1 + go, dA1 + lo);
  };
  auto stageB = [&](int buf, int kh, int kt) {
    const int lo = buf * 32768 + kh * 16384;
    const int go = kt * 128 + kh * 64;
    gload_lds16(pB0 + go, dB0 + lo);
    gload_lds16(pB1 + go, dB1 + lo);
  };

  const int lane = tid & 63;
  const int wv = tid >> 6;
  const int wr = (wv >> 2) * 128;   // wave row offset (2 M-waves)
  const int wc = (wv & 3) * 64;     // wave col offset (4 N-waves)
  // per-lane LDS read offset inside a (buf,kh) slot: row lane&15, swizzled granule
  const int aoff = ((lane & 15) * 64) + ((((lane >> 4) ^ ((lane >> 1) & 3)) & 3) * 16);

  f32x4 acc[8][4];
#pragma unroll
  for (int mi = 0; mi < 8; ++mi)
#pragma unroll
    for (int ni = 0; ni < 4; ++ni)
      acc[mi][ni] = (f32x4){0.f, 0.f, 0.f, 0.f};

  // ---- prologue: stage all 4 slots of tile 0 into buf0; wait k0, keep k1 in flight
  stageA(0, 0, 0); stageB(0, 0, 0); stageA(0, 1, 0); stageB(0, 1, 0);
  asm volatile("s_waitcnt vmcnt(4)" ::: "memory");
  __builtin_amdgcn_s_barrier();

  short8 a[4], b[4];

  for (int kt = 0; kt < KT; ++kt) {
    const int cur = kt & 1;
    const char* Ab = sA + cur * 32768;
    const char* Bb = sB + cur * 32768;
    const bool st = (kt + 1 < KT);

    // ======== phase 0: ks=0, mi 0-3 (reads B k0 + A k0 lower) ========
#pragma unroll
    for (int ni = 0; ni < 4; ++ni)
      b[ni] = *(const short8*)(Bb + (wc + ni * 16) * 64 + aoff);
#pragma unroll
    for (int mi = 0; mi < 4; ++mi)
      a[mi] = *(const short8*)(Ab + (wr + mi * 16) * 64 + aoff);
    if (st) stageA(cur ^ 1, 0, kt + 1);
    __builtin_amdgcn_s_barrier();
    asm volatile("s_waitcnt lgkmcnt(0)" ::: "memory");
    __builtin_amdgcn_sched_barrier(0);
    __builtin_amdgcn_s_setprio(1);
#pragma unroll
    for (int mi = 0; mi < 4; ++mi)
#pragma unroll
      for (int ni = 0; ni < 4; ++ni)
        acc[mi][ni] = MFMA16(a[mi], b[ni], acc[mi][ni], 0, 0, 0);
    __builtin_amdgcn_s_setprio(0);
    __builtin_amdgcn_s_barrier();

    // ======== phase 1: ks=0, mi 4-7 (B k0 reused from regs) ========
#pragma unroll
    for (int mi = 0; mi < 4; ++mi)
      a[mi] = *(const short8*)(Ab + (wr + 64 + mi * 16) * 64 + aoff);
    if (st) stageB(cur ^ 1, 0, kt + 1);
    __builtin_amdgcn_s_barrier();
    asm volatile("s_waitcnt lgkmcnt(0)" ::: "memory");
    __builtin_amdgcn_sched_barrier(0);
    __builtin_amdgcn_s_setprio(1);
#pragma unroll
    for (int mi = 0; mi < 4; ++mi)
#pragma unroll
      for (int ni = 0; ni < 4; ++ni)
        acc[4 + mi][ni] = MFMA16(a[mi], b[ni], acc[4 + mi][ni], 0, 0, 0);
    __builtin_amdgcn_s_setprio(0);
    if (st) asm volatile("s_waitcnt vmcnt(4)" ::: "memory");  // k1(t) landed
    else    asm volatile("s_waitcnt vmcnt(0)" ::: "memory");
    __builtin_amdgcn_s_barrier();

    // ======== phase 2: ks=1, mi 0-3 (reads B k1 + A k1 lower) ========
#pragma unroll
    for (int ni = 0; ni < 4; ++ni)
      b[ni] = *(const short8*)(Bb + 16384 + (wc + ni * 16) * 64 + aoff);
#pragma unroll
    for (int mi = 0; mi < 4; ++mi)
      a[mi] = *(const short8*)(Ab + 16384 + (wr + mi * 16) * 64 + aoff);
    if (st) stageA(cur ^ 1, 1, kt + 1);
    __builtin_amdgcn_s_barrier();
    asm volatile("s_waitcnt lgkmcnt(0)" ::: "memory");
    __builtin_amdgcn_sched_barrier(0);
    __builtin_amdgcn_s_setprio(1);
#pragma unroll
    for (int mi = 0; mi < 4; ++mi)
#pragma unroll
      for (int ni = 0; ni < 4; ++ni)
        acc[mi][ni] = MFMA16(a[mi], b[ni], acc[mi][ni], 0, 0, 0);
    __builtin_amdgcn_s_setprio(0);
    __builtin_amdgcn_s_barrier();

    // ======== phase 3: ks=1, mi 4-7 ========
#pragma unroll
    for (int mi = 0; mi < 4; ++mi)
      a[mi] = *(const short8*)(Ab + 16384 + (wr + 64 + mi * 16) * 64 + aoff);
    if (st) stageB(cur ^ 1, 1, kt + 1);
    __builtin_amdgcn_s_barrier();
    asm volatile("s_waitcnt lgkmcnt(0)" ::: "memory");
    __builtin_amdgcn_sched_barrier(0);
    __builtin_amdgcn_s_setprio(1);
#pragma unroll
    for (int mi = 0; mi < 4; ++mi)
#pragma unroll
      for (int ni = 0; ni < 4; ++ni)
        acc[4 + mi][ni] = MFMA16(a[mi], b[ni], acc[4 + mi][ni], 0, 0, 0);
    __builtin_amdgcn_s_setprio(0);
    if (st) asm volatile("s_waitcnt vmcnt(4)" ::: "memory");  // k0(t+1) landed
    else    asm volatile("s_waitcnt vmcnt(0)" ::: "memory");
    __builtin_amdgcn_s_barrier();
  }

  // ---- epilogue: bias + relu + gate-weight, atomicAdd into pre-zeroed out.
  // C/D layout (m89-verified): col = lane&15, row = (lane>>4)*4 + reg.
  const int cvalid = ce - row0;
#pragma unroll
  for (int mi = 0; mi < 8; ++mi) {
    int lr0 = wr + mi * 16 + (lane >> 4) * 4;
#pragma unroll
    for (int ni = 0; ni < 4; ++ni) {
      int col = bn0 + wc + ni * 16 + (lane & 15);
      float bv = be[e * DIM + col];
#pragma unroll
      for (int q = 0; q < 4; ++q) {
        int lr = lr0 + q;
        if (lr < cvalid) {
          float v = fmaxf(acc[mi][ni][q] + bv, 0.f) * sWt[lr];
          atomicAdd(out + (size_t)sTok[lr] * DIM + col, v);
        }
      }
    }
  }
}

extern "C" void kernel_launch(void* const* d_in, const int* in_sizes, int n_in,
                              void* d_out, int out_size, void* d_ws, size_t ws_size,
                              hipStream_t stream) {
  const float* x  = (const float*)d_in[0];
  const float* We = (const float*)d_in[1];
  const float* be = (const float*)d_in[2];
  const float* Wg = (const float*)d_in[3];
  const float* bg = (const float*)d_in[4];
  float* out = (float*)d_out;
  char* ws = (char*)d_ws;

  int*   cnt = (int*)(ws + OFF_CNT);
  int*   tok = (int*)(ws + OFF_TOK);
  float* wl  = (float*)(ws + OFF_WL);
  __hip_bfloat16* xb = (__hip_bfloat16*)(ws + OFF_XB);
  __hip_bfloat16* wb = (__hip_bfloat16*)(ws + OFF_WB);

  hipMemsetAsync(cnt, 0, 1024, stream);
  hipMemsetAsync(out, 0, (size_t)N_TOK * DIM * sizeof(float), stream);

  prep_kernel<<<4096, 256, 0, stream>>>(x, We, Wg, bg, xb, wb, cnt, tok, wl);
  moe_gemm<<<2048, 512, 0, stream>>>(xb, wb, be, cnt, tok, wl, out);
}

// Round 5
// 697.234 us; speedup vs baseline: 1.2041x; 1.2041x over previous
//
#include <hip/hip_runtime.h>
#include <hip/hip_bf16.h>
#include <stdint.h>

// MoE: N=8192 tokens, D=2048, E=8 experts, top-2 routing.
// prep (gate: choice+weights, fused x->bf16 | W->bf16) -> build_lists (1 block,
// ballot scan, zero atomics) -> grouped bf16 MFMA GEMM 256x256 2-phase dbuf
// (round-2 proven structure) with fused bias+ReLU+gate-weight epilogue and
// fp32 atomicAdd combine into pre-zeroed out.
// Workspace ~101.5 MB (round-3 footprint; 225 MB r4 layout overflowed ws -> crash).

#define N_TOK 8192
#define DIM   2048
#define NEXP  8

#define BM 256
#define BN 256
#define BK 64
#define KT (DIM / BK)   // 32 K-steps

typedef __attribute__((ext_vector_type(8))) short short8;
typedef __attribute__((ext_vector_type(4))) float f32x4;

// ---- workspace layout (bytes) ----
#define OFF_CNT   0                                   // 8 ints
#define OFF_CH    128                                 // N_TOK ints
#define OFF_GW    (OFF_CH  + 4*N_TOK)                 // 2*N_TOK floats
#define OFF_TOK   (OFF_GW  + 8*N_TOK)                 // NEXP*N_TOK ints
#define OFF_WL    (OFF_TOK + 4*N_TOK*NEXP)            // NEXP*N_TOK floats
#define OFF_XB    (OFF_WL  + 4*N_TOK*NEXP)            // N*D bf16 (34 MB)
#define OFF_WB    (OFF_XB + (size_t)N_TOK*DIM*2)      // E*D*D bf16 (67 MB)
// end = OFF_WB + 67.1 MB ~= 101.5 MB  (fits: rounds 1-3 ran at 101.4 MB)

__device__ __forceinline__ void gload_lds16(const void* g, void* l) {
  __builtin_amdgcn_global_load_lds(
      (const __attribute__((address_space(1))) void*)g,
      (__attribute__((address_space(3))) void*)l, 16, 0, 0);
}

// ---------------- prep: blocks [0,2048) = gate (+ x->bf16); [2048,4096) = W->bf16 ---
__global__ __launch_bounds__(256) void prep_kernel(
    const float* __restrict__ x, const float* __restrict__ We,
    const float* __restrict__ wg, const float* __restrict__ bg,
    __hip_bfloat16* __restrict__ xb, __hip_bfloat16* __restrict__ wb,
    int* __restrict__ choice, float* __restrict__ gw) {
  if (blockIdx.x >= N_TOK / 4) {
    const int n4 = NEXP * DIM * DIM / 4;
    const int stride = 2048 * 256;
    for (int i = (blockIdx.x - N_TOK / 4) * 256 + threadIdx.x; i < n4; i += stride) {
      float4 v = reinterpret_cast<const float4*>(We)[i];
      union { ushort4 u; __hip_bfloat16 h[4]; } cv;
      cv.h[0] = __float2bfloat16(v.x);
      cv.h[1] = __float2bfloat16(v.y);
      cv.h[2] = __float2bfloat16(v.z);
      cv.h[3] = __float2bfloat16(v.w);
      reinterpret_cast<ushort4*>(wb)[i] = cv.u;
    }
    return;
  }
  // ---- gating: one wave per token, fp32; fused x->bf16 cast; NO atomics ----
  const int wave = threadIdx.x >> 6;
  const int lane = threadIdx.x & 63;
  const int t = blockIdx.x * 4 + wave;
  const float4* xr = reinterpret_cast<const float4*>(x + (size_t)t * DIM);
  ushort4* xo = reinterpret_cast<ushort4*>(xb + (size_t)t * DIM);
  float acc[NEXP];
#pragma unroll
  for (int e = 0; e < NEXP; ++e) acc[e] = 0.f;
#pragma unroll
  for (int j = 0; j < DIM / 4 / 64; ++j) {     // 8 iters
    float4 xv = xr[lane + 64 * j];
    union { ushort4 u; __hip_bfloat16 h[4]; } cv;
    cv.h[0] = __float2bfloat16(xv.x);
    cv.h[1] = __float2bfloat16(xv.y);
    cv.h[2] = __float2bfloat16(xv.z);
    cv.h[3] = __float2bfloat16(xv.w);
    xo[lane + 64 * j] = cv.u;
#pragma unroll
    for (int e = 0; e < NEXP; ++e) {
      float4 gv = reinterpret_cast<const float4*>(wg + (size_t)e * DIM)[lane + 64 * j];
      acc[e] += xv.x * gv.x + xv.y * gv.y + xv.z * gv.z + xv.w * gv.w;
    }
  }
#pragma unroll
  for (int e = 0; e < NEXP; ++e) {
    float v = acc[e];
#pragma unroll
    for (int off = 32; off > 0; off >>= 1) v += __shfl_down(v, off);
    acc[e] = v;
  }
  if (lane == 0) {
    float lg[NEXP];
#pragma unroll
    for (int e = 0; e < NEXP; ++e) lg[e] = acc[e] + bg[e];
    float m = lg[0];
#pragma unroll
    for (int e = 1; e < NEXP; ++e) m = fmaxf(m, lg[e]);
    float s = 0.f, w[NEXP];
#pragma unroll
    for (int e = 0; e < NEXP; ++e) { w[e] = expf(lg[e] - m); s += w[e]; }
    float inv = 1.f / s;
    int i0 = 0;
#pragma unroll
    for (int e = 1; e < NEXP; ++e) if (lg[e] > lg[i0]) i0 = e;
    int i1 = -1;
#pragma unroll
    for (int e = 0; e < NEXP; ++e)
      if (e != i0 && (i1 < 0 || lg[e] > lg[i1])) i1 = e;
    choice[t] = i0 | (i1 << 8);
    gw[2 * t]     = w[i0] * inv;
    gw[2 * t + 1] = w[i1] * inv;
  }
}

// ---------------- build lists: 1 block, 512 threads; wave w = expert w ------------
// Single-pass ballot scan: every lane's running p is the whole-wave popcount, so
// each wave deterministically compacts its expert's tokens in increasing-t order.
// Zero atomics, zero LDS. lanemask_lt = bits strictly below lane.
__global__ __launch_bounds__(512) void build_lists(
    const int* __restrict__ choice, const float* __restrict__ gw,
    int* __restrict__ cnt, int* __restrict__ toklist, float* __restrict__ wlist) {
  const int w = threadIdx.x >> 6;
  const int lane = threadIdx.x & 63;
  const unsigned long long lmask = (lane == 0) ? 0ull : (~0ull >> (64 - lane));
  int p = 0;
  for (int it = 0; it < N_TOK / 64; ++it) {
    int t = it * 64 + lane;
    int ch = choice[t];
    unsigned long long m0 = __ballot((ch & 255) == w);
    if ((ch & 255) == w) {
      int r = p + __popcll(m0 & lmask);
      toklist[w * N_TOK + r] = t;
      wlist[w * N_TOK + r] = gw[2 * t];
    }
    p += __popcll(m0);
    unsigned long long m1 = __ballot(((ch >> 8) & 255) == w);
    if (((ch >> 8) & 255) == w) {
      int r = p + __popcll(m1 & lmask);
      toklist[w * N_TOK + r] = t;
      wlist[w * N_TOK + r] = gw[2 * t + 1];
    }
    p += __popcll(m1);
  }
  if (lane == 0) cnt[w] = p;
}

// ---------------- grouped GEMM: C = relu(Xg @ We^T + be) * wt, atomicAdd to out ----
// Round-2 proven structure: 2048 blocks XCD-swizzled (expert e -> XCD e), 512
// threads = 8 waves (2Mx4N), 256x256 tile, BK=64 double-buffer 2-phase.
__global__ __launch_bounds__(512, 2) void moe_gemm(
    const __hip_bfloat16* __restrict__ xb, const __hip_bfloat16* __restrict__ wb,
    const float* __restrict__ be, const int* __restrict__ cnt,
    const int* __restrict__ toklist, const float* __restrict__ wlist,
    float* __restrict__ out) {
  const int p = blockIdx.x;                 // 0..2047
  const int l = (p & 7) * 256 + (p >> 3);   // bijective XCD-chunked remap
  const int e  = l >> 8;
  const int ct = (l >> 5) & 7;
  const int tr = l & 31;
  const int ce = cnt[e];
  const int row0 = tr * BM;
  if (row0 >= ce) return;                   // uniform early-exit
  const int bn0 = ct * BN;

  __shared__ __align__(16) __hip_bfloat16 sA[2][BM * BK];  // 2 x 32 KB
  __shared__ __align__(16) __hip_bfloat16 sB[2][BN * BK];  // 2 x 32 KB
  __shared__ int   sTok[BM];
  __shared__ float sWt[BM];

  const int tid = threadIdx.x;
  if (tid < BM) {
    int r = row0 + tid;
    bool valid = r < ce;
    sTok[tid] = valid ? toklist[e * N_TOK + r] : 0;
    sWt[tid]  = valid ? wlist[e * N_TOK + r] : 0.f;
  }
  __syncthreads();

  // Staging sources. LDS dest LINEAR (global_load_lds rule); XOR granule swizzle
  // (g = pg ^ (r&7), 16B granules in 128B rows) on the GLOBAL source; reads apply
  // the same XOR (involution; verified rounds 1-2: pass, 0 bank conflicts).
  const char* srcA[4];
  const char* srcB[4];
#pragma unroll
  for (int n = 0; n < 4; ++n) {
    int cch = tid + 512 * n;  // 16B chunk id 0..2047
    int r = cch >> 3;         // tile row 0..255
    int pg = cch & 7;         // physical granule
    int g = pg ^ (r & 7);     // logical (source) granule
    srcA[n] = (const char*)(xb + (size_t)sTok[r] * DIM + g * 8);
    srcB[n] = (const char*)(wb + (size_t)(e * DIM + bn0 + r) * DIM + g * 8);
  }

  const int lane = tid & 63;
  const int wv = tid >> 6;
  const int wr = (wv >> 2) * 128;   // wave row offset (2 M-waves)
  const int wc = (wv & 3) * 64;     // wave col offset (4 N-waves)

  f32x4 acc[8][4];
#pragma unroll
  for (int mi = 0; mi < 8; ++mi)
#pragma unroll
    for (int ni = 0; ni < 4; ++ni)
      acc[mi][ni] = (f32x4){0.f, 0.f, 0.f, 0.f};

  auto stage = [&](int buf, int kt) {
    const int koff = kt * (BK * 2);   // bytes along K
#pragma unroll
    for (int n = 0; n < 4; ++n) {
      gload_lds16(srcA[n] + koff, (char*)sA[buf] + (tid + 512 * n) * 16);
      gload_lds16(srcB[n] + koff, (char*)sB[buf] + (tid + 512 * n) * 16);
    }
  };

  stage(0, 0);
  __syncthreads();

  int cur = 0;
  for (int kt = 0; kt < KT; ++kt) {
    if (kt + 1 < KT) stage(cur ^ 1, kt + 1);   // issue next-tile loads FIRST
#pragma unroll
    for (int ks = 0; ks < 2; ++ks) {
      const int gbase = ks * 4 + (lane >> 4);
      short8 bfr[4];
#pragma unroll
      for (int i = 0; i < 4; ++i) {
        int rB = wc + i * 16 + (lane & 15);
        bfr[i] = *(const short8*)((const char*)sB[cur] + rB * 128 +
                                  ((gbase ^ (rB & 7)) << 4));
      }
#pragma unroll
      for (int mi = 0; mi < 8; ++mi) {
        int rA = wr + mi * 16 + (lane & 15);
        short8 a = *(const short8*)((const char*)sA[cur] + rA * 128 +
                                    ((gbase ^ (rA & 7)) << 4));
#pragma unroll
        for (int ni = 0; ni < 4; ++ni)
          acc[mi][ni] = __builtin_amdgcn_mfma_f32_16x16x32_bf16(
              a, bfr[ni], acc[mi][ni], 0, 0, 0);
      }
    }
    __syncthreads();
    cur ^= 1;
  }

  // epilogue: bias + relu + gate-weight, atomicAdd into pre-zeroed out.
  // C/D layout (m89-verified): col = lane&15, row = (lane>>4)*4 + reg.
  const int cvalid = ce - row0;
#pragma unroll
  for (int mi = 0; mi < 8; ++mi) {
    int lr0 = wr + mi * 16 + (lane >> 4) * 4;
#pragma unroll
    for (int ni = 0; ni < 4; ++ni) {
      int col = bn0 + wc + ni * 16 + (lane & 15);
      float bv = be[e * DIM + col];
#pragma unroll
      for (int q = 0; q < 4; ++q) {
        int lr = lr0 + q;
        if (lr < cvalid) {
          float v = fmaxf(acc[mi][ni][q] + bv, 0.f) * sWt[lr];
          atomicAdd(out + (size_t)sTok[lr] * DIM + col, v);
        }
      }
    }
  }
}

extern "C" void kernel_launch(void* const* d_in, const int* in_sizes, int n_in,
                              void* d_out, int out_size, void* d_ws, size_t ws_size,
                              hipStream_t stream) {
  const float* x  = (const float*)d_in[0];
  const float* We = (const float*)d_in[1];
  const float* be = (const float*)d_in[2];
  const float* Wg = (const float*)d_in[3];
  const float* bg = (const float*)d_in[4];
  float* out = (float*)d_out;
  char* ws = (char*)d_ws;

  int*   cnt = (int*)(ws + OFF_CNT);
  int*   ch  = (int*)(ws + OFF_CH);
  float* gw  = (float*)(ws + OFF_GW);
  int*   tok = (int*)(ws + OFF_TOK);
  float* wl  = (float*)(ws + OFF_WL);
  __hip_bfloat16* xb = (__hip_bfloat16*)(ws + OFF_XB);
  __hip_bfloat16* wb = (__hip_bfloat16*)(ws + OFF_WB);

  hipMemsetAsync(out, 0, (size_t)N_TOK * DIM * sizeof(float), stream);

  prep_kernel<<<4096, 256, 0, stream>>>(x, We, Wg, bg, xb, wb, ch, gw);
  build_lists<<<1, 512, 0, stream>>>(ch, gw, cnt, tok, wl);
  moe_gemm<<<2048, 512, 0, stream>>>(xb, wb, be, cnt, tok, wl, out);
}

// Round 6
// 584.039 us; speedup vs baseline: 1.4374x; 1.1938x over previous
//
#include <hip/hip_runtime.h>
#include <hip/hip_bf16.h>
#include <stdint.h>

// MoE: N=8192 tokens, D=2048, E=8 experts, top-2 routing.
// prep (gate: choice+weights, fused x->bf16 | W->bf16) -> build_lists (1 block,
// ballot scan, zero atomics) -> grouped bf16 MFMA GEMM, m97 structure:
// 128x128 tile, 4 waves, single-buffered LDS (33 KB -> 4 blocks/CU for
// cross-block stall hiding), XCD-chunked + 4x4-supergroup block ordering,
// fused bias+ReLU+gate-weight epilogue, fp32 atomicAdd into pre-zeroed out.
// Workspace ~101.5 MB (known-safe footprint).

#define N_TOK 8192
#define DIM   2048
#define NEXP  8

#define BM 128
#define BN 128
#define BK 64
#define KT (DIM / BK)   // 32 K-steps

typedef __attribute__((ext_vector_type(8))) short short8;
typedef __attribute__((ext_vector_type(4))) float f32x4;

// ---- workspace layout (bytes) ----
#define OFF_CNT   0                                   // 8 ints
#define OFF_CH    128                                 // N_TOK ints
#define OFF_GW    (OFF_CH  + 4*N_TOK)                 // 2*N_TOK floats
#define OFF_TOK   (OFF_GW  + 8*N_TOK)                 // NEXP*N_TOK ints
#define OFF_WL    (OFF_TOK + 4*N_TOK*NEXP)            // NEXP*N_TOK floats
#define OFF_XB    (OFF_WL  + 4*N_TOK*NEXP)            // N*D bf16 (34 MB)
#define OFF_WB    (OFF_XB + (size_t)N_TOK*DIM*2)      // E*D*D bf16 (67 MB)
// end ~= 101.5 MB

__device__ __forceinline__ void gload_lds16(const void* g, void* l) {
  __builtin_amdgcn_global_load_lds(
      (const __attribute__((address_space(1))) void*)g,
      (__attribute__((address_space(3))) void*)l, 16, 0, 0);
}

// ---------------- prep: blocks [0,2048) = gate (+ x->bf16); [2048,4096) = W->bf16 ---
__global__ __launch_bounds__(256) void prep_kernel(
    const float* __restrict__ x, const float* __restrict__ We,
    const float* __restrict__ wg, const float* __restrict__ bg,
    __hip_bfloat16* __restrict__ xb, __hip_bfloat16* __restrict__ wb,
    int* __restrict__ choice, float* __restrict__ gw) {
  if (blockIdx.x >= N_TOK / 4) {
    const int n4 = NEXP * DIM * DIM / 4;
    const int stride = 2048 * 256;
    for (int i = (blockIdx.x - N_TOK / 4) * 256 + threadIdx.x; i < n4; i += stride) {
      float4 v = reinterpret_cast<const float4*>(We)[i];
      union { ushort4 u; __hip_bfloat16 h[4]; } cv;
      cv.h[0] = __float2bfloat16(v.x);
      cv.h[1] = __float2bfloat16(v.y);
      cv.h[2] = __float2bfloat16(v.z);
      cv.h[3] = __float2bfloat16(v.w);
      reinterpret_cast<ushort4*>(wb)[i] = cv.u;
    }
    return;
  }
  // ---- gating: one wave per token, fp32; fused x->bf16 cast; NO atomics ----
  const int wave = threadIdx.x >> 6;
  const int lane = threadIdx.x & 63;
  const int t = blockIdx.x * 4 + wave;
  const float4* xr = reinterpret_cast<const float4*>(x + (size_t)t * DIM);
  ushort4* xo = reinterpret_cast<ushort4*>(xb + (size_t)t * DIM);
  float acc[NEXP];
#pragma unroll
  for (int e = 0; e < NEXP; ++e) acc[e] = 0.f;
#pragma unroll
  for (int j = 0; j < DIM / 4 / 64; ++j) {     // 8 iters
    float4 xv = xr[lane + 64 * j];
    union { ushort4 u; __hip_bfloat16 h[4]; } cv;
    cv.h[0] = __float2bfloat16(xv.x);
    cv.h[1] = __float2bfloat16(xv.y);
    cv.h[2] = __float2bfloat16(xv.z);
    cv.h[3] = __float2bfloat16(xv.w);
    xo[lane + 64 * j] = cv.u;
#pragma unroll
    for (int e = 0; e < NEXP; ++e) {
      float4 gv = reinterpret_cast<const float4*>(wg + (size_t)e * DIM)[lane + 64 * j];
      acc[e] += xv.x * gv.x + xv.y * gv.y + xv.z * gv.z + xv.w * gv.w;
    }
  }
#pragma unroll
  for (int e = 0; e < NEXP; ++e) {
    float v = acc[e];
#pragma unroll
    for (int off = 32; off > 0; off >>= 1) v += __shfl_down(v, off);
    acc[e] = v;
  }
  if (lane == 0) {
    float lg[NEXP];
#pragma unroll
    for (int e = 0; e < NEXP; ++e) lg[e] = acc[e] + bg[e];
    float m = lg[0];
#pragma unroll
    for (int e = 1; e < NEXP; ++e) m = fmaxf(m, lg[e]);
    float s = 0.f, w[NEXP];
#pragma unroll
    for (int e = 0; e < NEXP; ++e) { w[e] = expf(lg[e] - m); s += w[e]; }
    float inv = 1.f / s;
    int i0 = 0;
#pragma unroll
    for (int e = 1; e < NEXP; ++e) if (lg[e] > lg[i0]) i0 = e;
    int i1 = -1;
#pragma unroll
    for (int e = 0; e < NEXP; ++e)
      if (e != i0 && (i1 < 0 || lg[e] > lg[i1])) i1 = e;
    choice[t] = i0 | (i1 << 8);
    gw[2 * t]     = w[i0] * inv;
    gw[2 * t + 1] = w[i1] * inv;
  }
}

// ---------------- build lists: 1 block, 512 threads; wave w = expert w ------------
__global__ __launch_bounds__(512) void build_lists(
    const int* __restrict__ choice, const float* __restrict__ gw,
    int* __restrict__ cnt, int* __restrict__ toklist, float* __restrict__ wlist) {
  const int w = threadIdx.x >> 6;
  const int lane = threadIdx.x & 63;
  const unsigned long long lmask = (lane == 0) ? 0ull : (~0ull >> (64 - lane));
  int p = 0;
  for (int it = 0; it < N_TOK / 64; ++it) {
    int t = it * 64 + lane;
    int ch = choice[t];
    unsigned long long m0 = __ballot((ch & 255) == w);
    if ((ch & 255) == w) {
      int r = p + __popcll(m0 & lmask);
      toklist[w * N_TOK + r] = t;
      wlist[w * N_TOK + r] = gw[2 * t];
    }
    p += __popcll(m0);
    unsigned long long m1 = __ballot(((ch >> 8) & 255) == w);
    if (((ch >> 8) & 255) == w) {
      int r = p + __popcll(m1 & lmask);
      toklist[w * N_TOK + r] = t;
      wlist[w * N_TOK + r] = gw[2 * t + 1];
    }
    p += __popcll(m1);
  }
  if (lane == 0) cnt[w] = p;
}

// ---------------- grouped GEMM: C = relu(Xg @ We^T + be) * wt, atomicAdd to out ----
// m97 structure: 128x128 tile, BK=64, 4 waves (2x2, 64x64 each), SINGLE-buffered
// 33 KB LDS -> 4 resident blocks/CU (cross-block overlap hides the per-step
// vmcnt drain at __syncthreads). 8192 blocks: XCD-chunked (expert e -> XCD e),
// within-XCD 4x4 supergroups (4 slots x 4 cts concurrent ~ 4 MB = one L2).
__global__ __launch_bounds__(256, 4) void moe_gemm(
    const __hip_bfloat16* __restrict__ xb, const __hip_bfloat16* __restrict__ wb,
    const float* __restrict__ be, const int* __restrict__ cnt,
    const int* __restrict__ toklist, const float* __restrict__ wlist,
    float* __restrict__ out) {
  const int p = blockIdx.x;                  // 0..8191
  const int l = (p & 7) * 1024 + (p >> 3);   // bijective XCD-chunked remap
  const int e = l >> 10;                     // expert -> XCD
  const int w = l & 1023;
  const int sg = w >> 4, dd = w & 15;        // 64 supergroups of 16 blocks
  const int slot = (sg >> 2) * 4 + (dd >> 2);  // 0..63 row-slot
  const int ct   = (sg & 3) * 4 + (dd & 3);    // 0..15 col-tile
  const int ce = cnt[e];
  const int row0 = slot * BM;
  if (row0 >= ce) return;                    // uniform early-exit
  const int bn0 = ct * BN;

  __shared__ __align__(16) __hip_bfloat16 sA[BM * BK];  // 16 KB
  __shared__ __align__(16) __hip_bfloat16 sB[BN * BK];  // 16 KB
  __shared__ int   sTok[BM];
  __shared__ float sWt[BM];

  const int tid = threadIdx.x;
  if (tid < BM) {
    int r = row0 + tid;
    bool valid = r < ce;
    sTok[tid] = valid ? toklist[e * N_TOK + r] : 0;
    sWt[tid]  = valid ? wlist[e * N_TOK + r] : 0.f;
  }
  __syncthreads();

  // Staging sources. LDS dest LINEAR (global_load_lds rule); XOR granule swizzle
  // (g = pg ^ (r&7), 16B granules in 128B rows) on the GLOBAL source; reads apply
  // the same XOR (involution; verified rounds 1-5: pass, 0 bank conflicts).
  const char* srcA[4];
  const char* srcB[4];
#pragma unroll
  for (int n = 0; n < 4; ++n) {
    int cch = tid + 256 * n;  // 16B chunk id 0..1023
    int r = cch >> 3;         // tile row 0..127
    int pg = cch & 7;         // physical granule
    int g = pg ^ (r & 7);     // logical (source) granule
    srcA[n] = (const char*)(xb + (size_t)sTok[r] * DIM + g * 8);
    srcB[n] = (const char*)(wb + (size_t)(e * DIM + bn0 + r) * DIM + g * 8);
  }

  const int lane = tid & 63;
  const int wv = tid >> 6;
  const int wr = (wv >> 1) * 64;   // wave row offset (2x2 waves)
  const int wc = (wv & 1) * 64;

  f32x4 acc[4][4];
#pragma unroll
  for (int mi = 0; mi < 4; ++mi)
#pragma unroll
    for (int ni = 0; ni < 4; ++ni)
      acc[mi][ni] = (f32x4){0.f, 0.f, 0.f, 0.f};

  for (int kt = 0; kt < KT; ++kt) {
    const int koff = kt * (BK * 2);   // bytes along K
#pragma unroll
    for (int n = 0; n < 4; ++n) {
      gload_lds16(srcA[n] + koff, (char*)sA + (tid + 256 * n) * 16);
      gload_lds16(srcB[n] + koff, (char*)sB + (tid + 256 * n) * 16);
    }
    __syncthreads();   // drains vmcnt(0); other resident blocks hide the stall
#pragma unroll
    for (int ks = 0; ks < 2; ++ks) {
      const int gbase = ks * 4 + (lane >> 4);
      short8 bfr[4];
#pragma unroll
      for (int i = 0; i < 4; ++i) {
        int rB = wc + i * 16 + (lane & 15);
        bfr[i] = *(const short8*)((const char*)sB + rB * 128 +
                                  ((gbase ^ (rB & 7)) << 4));
      }
#pragma unroll
      for (int mi = 0; mi < 4; ++mi) {
        int rA = wr + mi * 16 + (lane & 15);
        short8 a = *(const short8*)((const char*)sA + rA * 128 +
                                    ((gbase ^ (rA & 7)) << 4));
#pragma unroll
        for (int ni = 0; ni < 4; ++ni)
          acc[mi][ni] = __builtin_amdgcn_mfma_f32_16x16x32_bf16(
              a, bfr[ni], acc[mi][ni], 0, 0, 0);
      }
    }
    __syncthreads();   // all waves done reading before next stage overwrites
  }

  // epilogue: bias + relu + gate-weight, atomicAdd into pre-zeroed out.
  // C/D layout (m89-verified): col = lane&15, row = (lane>>4)*4 + reg.
  const int cvalid = ce - row0;
#pragma unroll
  for (int mi = 0; mi < 4; ++mi) {
    int lr0 = wr + mi * 16 + (lane >> 4) * 4;
#pragma unroll
    for (int ni = 0; ni < 4; ++ni) {
      int col = bn0 + wc + ni * 16 + (lane & 15);
      float bv = be[e * DIM + col];
#pragma unroll
      for (int q = 0; q < 4; ++q) {
        int lr = lr0 + q;
        if (lr < cvalid) {
          float v = fmaxf(acc[mi][ni][q] + bv, 0.f) * sWt[lr];
          atomicAdd(out + (size_t)sTok[lr] * DIM + col, v);
        }
      }
    }
  }
}

extern "C" void kernel_launch(void* const* d_in, const int* in_sizes, int n_in,
                              void* d_out, int out_size, void* d_ws, size_t ws_size,
                              hipStream_t stream) {
  const float* x  = (const float*)d_in[0];
  const float* We = (const float*)d_in[1];
  const float* be = (const float*)d_in[2];
  const float* Wg = (const float*)d_in[3];
  const float* bg = (const float*)d_in[4];
  float* out = (float*)d_out;
  char* ws = (char*)d_ws;

  int*   cnt = (int*)(ws + OFF_CNT);
  int*   ch  = (int*)(ws + OFF_CH);
  float* gw  = (float*)(ws + OFF_GW);
  int*   tok = (int*)(ws + OFF_TOK);
  float* wl  = (float*)(ws + OFF_WL);
  __hip_bfloat16* xb = (__hip_bfloat16*)(ws + OFF_XB);
  __hip_bfloat16* wb = (__hip_bfloat16*)(ws + OFF_WB);

  hipMemsetAsync(out, 0, (size_t)N_TOK * DIM * sizeof(float), stream);

  prep_kernel<<<4096, 256, 0, stream>>>(x, We, Wg, bg, xb, wb, ch, gw);
  build_lists<<<1, 512, 0, stream>>>(ch, gw, cnt, tok, wl);
  moe_gemm<<<8192, 256, 0, stream>>>(xb, wb, be, cnt, tok, wl, out);
}

// Round 7
// 553.257 us; speedup vs baseline: 1.5174x; 1.0556x over previous
//
#include <hip/hip_runtime.h>
#include <hip/hip_bf16.h>
#include <stdint.h>

// MoE: N=8192 tokens, D=2048, E=8 experts, top-2 routing.
// prep (gate: choice+weights, fused x->bf16 | W->bf16) -> build_lists (1 block,
// int4-vectorized ballot scatter, order-free, zero atomics) -> grouped bf16 MFMA
// GEMM, m97 structure: 128x128 tile, 4 waves, single-buffered 33 KB LDS
// (4 blocks/CU cross-block stall hiding), XCD-chunked + 4x4-supergroup ordering,
// fused bias+ReLU+gate-weight epilogue, fp32 atomicAdd into pre-zeroed out.
// Workspace ~101.5 MB (known-safe footprint).

#define N_TOK 8192
#define DIM   2048
#define NEXP  8

#define BM 128
#define BN 128
#define BK 64
#define KT (DIM / BK)   // 32 K-steps

typedef __attribute__((ext_vector_type(8))) short short8;
typedef __attribute__((ext_vector_type(4))) float f32x4;

// ---- workspace layout (bytes) ----
#define OFF_CNT   0                                   // 8 ints
#define OFF_CH    128                                 // N_TOK ints
#define OFF_GW    (OFF_CH  + 4*N_TOK)                 // 2*N_TOK floats
#define OFF_TOK   (OFF_GW  + 8*N_TOK)                 // NEXP*N_TOK ints
#define OFF_WL    (OFF_TOK + 4*N_TOK*NEXP)            // NEXP*N_TOK floats
#define OFF_XB    (OFF_WL  + 4*N_TOK*NEXP)            // N*D bf16 (34 MB)
#define OFF_WB    (OFF_XB + (size_t)N_TOK*DIM*2)      // E*D*D bf16 (67 MB)
// end ~= 101.5 MB

__device__ __forceinline__ void gload_lds16(const void* g, void* l) {
  __builtin_amdgcn_global_load_lds(
      (const __attribute__((address_space(1))) void*)g,
      (__attribute__((address_space(3))) void*)l, 16, 0, 0);
}

// ---------------- prep: blocks [0,2048) = gate (+ x->bf16); [2048,4096) = W->bf16 ---
__global__ __launch_bounds__(256) void prep_kernel(
    const float* __restrict__ x, const float* __restrict__ We,
    const float* __restrict__ wg, const float* __restrict__ bg,
    __hip_bfloat16* __restrict__ xb, __hip_bfloat16* __restrict__ wb,
    int* __restrict__ choice, float* __restrict__ gw) {
  if (blockIdx.x >= N_TOK / 4) {
    const int n4 = NEXP * DIM * DIM / 4;
    const int stride = 2048 * 256;
    for (int i = (blockIdx.x - N_TOK / 4) * 256 + threadIdx.x; i < n4; i += stride) {
      float4 v = reinterpret_cast<const float4*>(We)[i];
      union { ushort4 u; __hip_bfloat16 h[4]; } cv;
      cv.h[0] = __float2bfloat16(v.x);
      cv.h[1] = __float2bfloat16(v.y);
      cv.h[2] = __float2bfloat16(v.z);
      cv.h[3] = __float2bfloat16(v.w);
      reinterpret_cast<ushort4*>(wb)[i] = cv.u;
    }
    return;
  }
  // ---- gating: one wave per token, fp32; fused x->bf16 cast; NO atomics ----
  const int wave = threadIdx.x >> 6;
  const int lane = threadIdx.x & 63;
  const int t = blockIdx.x * 4 + wave;
  const float4* xr = reinterpret_cast<const float4*>(x + (size_t)t * DIM);
  ushort4* xo = reinterpret_cast<ushort4*>(xb + (size_t)t * DIM);
  float acc[NEXP];
#pragma unroll
  for (int e = 0; e < NEXP; ++e) acc[e] = 0.f;
#pragma unroll
  for (int j = 0; j < DIM / 4 / 64; ++j) {     // 8 iters
    float4 xv = xr[lane + 64 * j];
    union { ushort4 u; __hip_bfloat16 h[4]; } cv;
    cv.h[0] = __float2bfloat16(xv.x);
    cv.h[1] = __float2bfloat16(xv.y);
    cv.h[2] = __float2bfloat16(xv.z);
    cv.h[3] = __float2bfloat16(xv.w);
    xo[lane + 64 * j] = cv.u;
#pragma unroll
    for (int e = 0; e < NEXP; ++e) {
      float4 gv = reinterpret_cast<const float4*>(wg + (size_t)e * DIM)[lane + 64 * j];
      acc[e] += xv.x * gv.x + xv.y * gv.y + xv.z * gv.z + xv.w * gv.w;
    }
  }
#pragma unroll
  for (int e = 0; e < NEXP; ++e) {
    float v = acc[e];
#pragma unroll
    for (int off = 32; off > 0; off >>= 1) v += __shfl_down(v, off);
    acc[e] = v;
  }
  if (lane == 0) {
    float lg[NEXP];
#pragma unroll
    for (int e = 0; e < NEXP; ++e) lg[e] = acc[e] + bg[e];
    float m = lg[0];
#pragma unroll
    for (int e = 1; e < NEXP; ++e) m = fmaxf(m, lg[e]);
    float s = 0.f, w[NEXP];
#pragma unroll
    for (int e = 0; e < NEXP; ++e) { w[e] = expf(lg[e] - m); s += w[e]; }
    float inv = 1.f / s;
    int i0 = 0;
#pragma unroll
    for (int e = 1; e < NEXP; ++e) if (lg[e] > lg[i0]) i0 = e;
    int i1 = -1;
#pragma unroll
    for (int e = 0; e < NEXP; ++e)
      if (e != i0 && (i1 < 0 || lg[e] > lg[i1])) i1 = e;
    choice[t] = i0 | (i1 << 8);
    gw[2 * t]     = w[i0] * inv;
    gw[2 * t + 1] = w[i1] * inv;
  }
}

// ---------------- build lists: 1 block, 512 threads; wave w = expert w ------------
// int4-vectorized ballot scatter (32 iters, 4 subword groups per load). List order
// within an expert is ARBITRARY (each entry carries its weight; epilogue atomicAdd
// order is nondeterministic anyway) -> no cross-iteration ordering constraint, so
// loads pipeline freely. Zero atomics, zero LDS.
__global__ __launch_bounds__(512) void build_lists(
    const int* __restrict__ choice, const float* __restrict__ gw,
    int* __restrict__ cnt, int* __restrict__ toklist, float* __restrict__ wlist) {
  const int w = threadIdx.x >> 6;
  const int lane = threadIdx.x & 63;
  const unsigned long long lmask = (lane == 0) ? 0ull : (~0ull >> (64 - lane));
  const int4* ch4 = reinterpret_cast<const int4*>(choice);
  const float2* gw2 = reinterpret_cast<const float2*>(gw);
  int p = 0;
  for (int it = 0; it < N_TOK / 256; ++it) {   // 32 iters
    int4 v = ch4[it * 64 + lane];
#pragma unroll
    for (int s = 0; s < 4; ++s) {
      int c = (s == 0) ? v.x : (s == 1) ? v.y : (s == 2) ? v.z : v.w;
      int t = it * 256 + 4 * lane + s;
      unsigned long long m0 = __ballot((c & 255) == w);
      if ((c & 255) == w) {
        int r = p + __popcll(m0 & lmask);
        toklist[w * N_TOK + r] = t;
        wlist[w * N_TOK + r] = gw2[t].x;
      }
      p += __popcll(m0);
      unsigned long long m1 = __ballot(((c >> 8) & 255) == w);
      if (((c >> 8) & 255) == w) {
        int r = p + __popcll(m1 & lmask);
        toklist[w * N_TOK + r] = t;
        wlist[w * N_TOK + r] = gw2[t].y;
      }
      p += __popcll(m1);
    }
  }
  if (lane == 0) cnt[w] = p;
}

// ---------------- grouped GEMM: C = relu(Xg @ We^T + be) * wt, atomicAdd to out ----
// m97 structure: 128x128 tile, BK=64, 4 waves (2x2, 64x64 each), SINGLE-buffered
// 33 KB LDS -> 4 resident blocks/CU (cross-block overlap hides the per-step
// vmcnt drain at __syncthreads). 8192 blocks: XCD-chunked (expert e -> XCD e),
// within-XCD 4x4 supergroups (4 slots x 4 cts concurrent ~ 4 MB = one L2).
__global__ __launch_bounds__(256, 4) void moe_gemm(
    const __hip_bfloat16* __restrict__ xb, const __hip_bfloat16* __restrict__ wb,
    const float* __restrict__ be, const int* __restrict__ cnt,
    const int* __restrict__ toklist, const float* __restrict__ wlist,
    float* __restrict__ out) {
  const int p = blockIdx.x;                  // 0..8191
  const int l = (p & 7) * 1024 + (p >> 3);   // bijective XCD-chunked remap
  const int e = l >> 10;                     // expert -> XCD
  const int w = l & 1023;
  const int sg = w >> 4, dd = w & 15;        // 64 supergroups of 16 blocks
  const int slot = (sg >> 2) * 4 + (dd >> 2);  // 0..63 row-slot
  const int ct   = (sg & 3) * 4 + (dd & 3);    // 0..15 col-tile
  const int ce = cnt[e];
  const int row0 = slot * BM;
  if (row0 >= ce) return;                    // uniform early-exit
  const int bn0 = ct * BN;

  __shared__ __align__(16) __hip_bfloat16 sA[BM * BK];  // 16 KB
  __shared__ __align__(16) __hip_bfloat16 sB[BN * BK];  // 16 KB
  __shared__ int   sTok[BM];
  __shared__ float sWt[BM];

  const int tid = threadIdx.x;
  if (tid < BM) {
    int r = row0 + tid;
    bool valid = r < ce;
    sTok[tid] = valid ? toklist[e * N_TOK + r] : 0;
    sWt[tid]  = valid ? wlist[e * N_TOK + r] : 0.f;
  }
  __syncthreads();

  // Staging sources. LDS dest LINEAR (global_load_lds rule); XOR granule swizzle
  // (g = pg ^ (r&7), 16B granules in 128B rows) on the GLOBAL source; reads apply
  // the same XOR (involution; verified rounds 1-6: pass, 0 bank conflicts).
  const char* srcA[4];
  const char* srcB[4];
#pragma unroll
  for (int n = 0; n < 4; ++n) {
    int cch = tid + 256 * n;  // 16B chunk id 0..1023
    int r = cch >> 3;         // tile row 0..127
    int pg = cch & 7;         // physical granule
    int g = pg ^ (r & 7);     // logical (source) granule
    srcA[n] = (const char*)(xb + (size_t)sTok[r] * DIM + g * 8);
    srcB[n] = (const char*)(wb + (size_t)(e * DIM + bn0 + r) * DIM + g * 8);
  }

  const int lane = tid & 63;
  const int wv = tid >> 6;
  const int wr = (wv >> 1) * 64;   // wave row offset (2x2 waves)
  const int wc = (wv & 1) * 64;

  f32x4 acc[4][4];
#pragma unroll
  for (int mi = 0; mi < 4; ++mi)
#pragma unroll
    for (int ni = 0; ni < 4; ++ni)
      acc[mi][ni] = (f32x4){0.f, 0.f, 0.f, 0.f};

  for (int kt = 0; kt < KT; ++kt) {
    const int koff = kt * (BK * 2);   // bytes along K
#pragma unroll
    for (int n = 0; n < 4; ++n) {
      gload_lds16(srcA[n] + koff, (char*)sA + (tid + 256 * n) * 16);
      gload_lds16(srcB[n] + koff, (char*)sB + (tid + 256 * n) * 16);
    }
    __syncthreads();   // drains vmcnt(0); other resident blocks hide the stall
#pragma unroll
    for (int ks = 0; ks < 2; ++ks) {
      const int gbase = ks * 4 + (lane >> 4);
      short8 bfr[4];
#pragma unroll
      for (int i = 0; i < 4; ++i) {
        int rB = wc + i * 16 + (lane & 15);
        bfr[i] = *(const short8*)((const char*)sB + rB * 128 +
                                  ((gbase ^ (rB & 7)) << 4));
      }
#pragma unroll
      for (int mi = 0; mi < 4; ++mi) {
        int rA = wr + mi * 16 + (lane & 15);
        short8 a = *(const short8*)((const char*)sA + rA * 128 +
                                    ((gbase ^ (rA & 7)) << 4));
#pragma unroll
        for (int ni = 0; ni < 4; ++ni)
          acc[mi][ni] = __builtin_amdgcn_mfma_f32_16x16x32_bf16(
              a, bfr[ni], acc[mi][ni], 0, 0, 0);
      }
    }
    __syncthreads();   // all waves done reading before next stage overwrites
  }

  // epilogue: bias + relu + gate-weight, atomicAdd into pre-zeroed out.
  // C/D layout (m89-verified): col = lane&15, row = (lane>>4)*4 + reg.
  const int cvalid = ce - row0;
#pragma unroll
  for (int mi = 0; mi < 4; ++mi) {
    int lr0 = wr + mi * 16 + (lane >> 4) * 4;
#pragma unroll
    for (int ni = 0; ni < 4; ++ni) {
      int col = bn0 + wc + ni * 16 + (lane & 15);
      float bv = be[e * DIM + col];
#pragma unroll
      for (int q = 0; q < 4; ++q) {
        int lr = lr0 + q;
        if (lr < cvalid) {
          float v = fmaxf(acc[mi][ni][q] + bv, 0.f) * sWt[lr];
          atomicAdd(out + (size_t)sTok[lr] * DIM + col, v);
        }
      }
    }
  }
}

extern "C" void kernel_launch(void* const* d_in, const int* in_sizes, int n_in,
                              void* d_out, int out_size, void* d_ws, size_t ws_size,
                              hipStream_t stream) {
  const float* x  = (const float*)d_in[0];
  const float* We = (const float*)d_in[1];
  const float* be = (const float*)d_in[2];
  const float* Wg = (const float*)d_in[3];
  const float* bg = (const float*)d_in[4];
  float* out = (float*)d_out;
  char* ws = (char*)d_ws;

  int*   cnt = (int*)(ws + OFF_CNT);
  int*   ch  = (int*)(ws + OFF_CH);
  float* gw  = (float*)(ws + OFF_GW);
  int*   tok = (int*)(ws + OFF_TOK);
  float* wl  = (float*)(ws + OFF_WL);
  __hip_bfloat16* xb = (__hip_bfloat16*)(ws + OFF_XB);
  __hip_bfloat16* wb = (__hip_bfloat16*)(ws + OFF_WB);

  hipMemsetAsync(out, 0, (size_t)N_TOK * DIM * sizeof(float), stream);

  prep_kernel<<<4096, 256, 0, stream>>>(x, We, Wg, bg, xb, wb, ch, gw);
  build_lists<<<1, 512, 0, stream>>>(ch, gw, cnt, tok, wl);
  moe_gemm<<<8192, 256, 0, stream>>>(xb, wb, be, cnt, tok, wl, out);
}